// Round 5
// baseline (212.925 us; speedup 1.0000x reference)
//
#include <hip/hip_runtime.h>
#include <math.h>

#define B_N 65536
#define K_N 1024
#define D_N 256
#define CAPW 768
#define NWV 4            // waves per block (256 threads); 32 rows/wave -> 128 rows/block

typedef __attribute__((ext_vector_type(8))) short bf16x8;
typedef __attribute__((ext_vector_type(4))) float f32x4;

// RNE float -> bf16 bits
__device__ __forceinline__ unsigned short f2bf(float f) {
    unsigned u = __float_as_uint(f);
    return (unsigned short)((u + 0x7FFFu + ((u >> 16) & 1u)) >> 16);
}
// monotone float <-> u32 order encoding
__device__ __forceinline__ unsigned encf(float f) {
    unsigned u = __float_as_uint(f);
    return u ^ ((unsigned)((int)u >> 31) | 0x80000000u);
}
__device__ __forceinline__ float decf(unsigned e) {
    unsigned u = (e & 0x80000000u) ? (e ^ 0x80000000u) : ~e;
    return __uint_as_float(u);
}
__device__ __forceinline__ void gload_lds16(const void* g, void* l) {
    __builtin_amdgcn_global_load_lds(
        (const __attribute__((address_space(1))) unsigned int*)g,
        (__attribute__((address_space(3))) unsigned int*)l, 16, 0, 0);
}

// THE exact dot chain (bit-identical to the chain validated rounds 1-5/8/11).
__device__ __forceinline__ float chain_dot(const float* __restrict__ zp,
                                           const float* __restrict__ wp) {
    float acc = 0.0f;
    #pragma unroll 1
    for (int j = 0; j < 64; ++j) {
        float4 za = *reinterpret_cast<const float4*>(zp + (j << 2));
        float4 wa = *reinterpret_cast<const float4*>(wp + (j << 2));
        acc = fmaf(za.x, wa.x, acc);
        acc = fmaf(za.y, wa.y, acc);
        acc = fmaf(za.z, wa.z, acc);
        acc = fmaf(za.w, wa.w, acc);
    }
    return acc;
}

// ---------------------------------------------------------------------------
// MFMA decode probe (validated rounds 8-11). flag: 0=H1, 1=swapped, 2=bad.
// ---------------------------------------------------------------------------
__device__ __forceinline__ int pA(int i, int k) {
    return ((i + k) & 15) - 7 + 9 * ((k >> 4) & 1);
}
__device__ __forceinline__ int pB(int j, int k) {
    return ((j + 3 * k) & 15) - 7 + 5 * ((k >> 4) & 1);
}

__global__ void mfma_probe_kernel(int* __restrict__ flag) {
    const int l = threadIdx.x & 63;
    const int c15 = l & 15, g = l >> 4;
    bf16x8 afr[8], bfr[8];
    #pragma unroll
    for (int m = 0; m < 8; ++m)
        #pragma unroll
        for (int e = 0; e < 8; ++e) {
            const int k = m * 32 + g * 8 + e;
            afr[m][e] = (short)f2bf((float)pA(c15, k));
            bfr[m][e] = (short)f2bf((float)pB(c15, k));
        }
    f32x4 acc = {0.f, 0.f, 0.f, 0.f};
    #pragma unroll
    for (int m = 0; m < 8; ++m)
        acc = __builtin_amdgcn_mfma_f32_16x16x32_bf16(afr[m], bfr[m], acc, 0, 0, 0);
    int h1 = 1, h2 = 1;
    #pragma unroll 1
    for (int reg = 0; reg < 4; ++reg) {
        const int q = 4 * g + reg;
        int e1 = 0, e2 = 0;
        for (int k = 0; k < 32; ++k) {        // patterns are 32-periodic in k
            e1 += pA(q, k) * pB(c15, k);
            e2 += pA(c15, k) * pB(q, k);
        }
        e1 *= 8; e2 *= 8;
        if (acc[reg] != (float)e1) h1 = 0;
        if (acc[reg] != (float)e2) h2 = 0;
    }
    h1 = __all(h1); h2 = __all(h2);
    if (threadIdx.x == 0) *flag = h1 ? 0 : (h2 ? 1 : 2);
}

// ---------------------------------------------------------------------------
// ww (validated tree) + bf16 codebook re-tiled for linear LDS fragment reads
// (validated r10/r11 layout).
// ---------------------------------------------------------------------------
__global__ void wprep_kernel(const float* __restrict__ w,
                             float* __restrict__ ww,
                             unsigned short* __restrict__ wb) {
    int wave = (int)((blockIdx.x * blockDim.x + threadIdx.x) >> 6);
    int lane = threadIdx.x & 63;
    if (wave >= K_N) return;
    const float4 v = *reinterpret_cast<const float4*>(w + ((size_t)wave << 8) + (lane << 2));
    float s = v.x * v.x + v.y * v.y + v.z * v.z + v.w * v.w;
    #pragma unroll
    for (int off = 32; off; off >>= 1) s += __shfl_xor(s, off, 64);
    if (lane == 0) ww[wave] = s;
    ushort4 b;
    b.x = f2bf(v.x); b.y = f2bf(v.y); b.z = f2bf(v.z); b.w = f2bf(v.w);
    const int mp = lane >> 3;
    const int gp = (lane >> 1) & 3;
    const int hp = (wave >> 4) & 1;
    const size_t off_b = (size_t)(wave >> 5) * 16384
        + (size_t)(((hp * 8 + mp) * 64 + gp * 16 + (wave & 15)) * 16)
        + (size_t)((lane & 1) * 8);
    *reinterpret_cast<ushort4*>((char*)wb + off_b) = b;
}

// ---------------------------------------------------------------------------
// Main kernel.
// r16: 2x rows per wave -> halve LDS read volume (the measured ~47us pipe
//   floor). Each wave owns 32 rows via TWO A-fragment sets; every
//   ds_read_b128 of a B fragment feeds 2 MFMAs. Blocks: 4 waves/256 thr/
//   128 rows, grid 512; LDS ~52 KB -> 3 blocks/CU (12 waves/CU) and 2x
//   per-wave ILP. Total ds_read_b128 2.23M -> 1.11M; MFMA/DMA unchanged.
//   Collection: row gets 5 bits in rc (fits ushort); CAPW 768/wave
//   (~240 expected, 3.2x headroom; overflow -> per-wave exact fallback).
//   Superset invariant unchanged (band >= 2x error bound), exact-chain
//   rescore + lowest-code tiebreak + loss-from-dist (r15) unchanged.
//   Reverted neutral r13/r14 pipeline complexity to the r12-proven
//   2-buffer STAGE/compute/__syncthreads schedule.
// ---------------------------------------------------------------------------
__global__ __launch_bounds__(256, 3)
void vq_mfma_kernel(const float* __restrict__ z, const float* __restrict__ w,
                    const unsigned short* __restrict__ wb,
                    const float* __restrict__ ww,
                    const int* __restrict__ flagp,
                    float* __restrict__ zq_out,
                    float* __restrict__ idxf_out,
                    double* __restrict__ partial) {
    __shared__ alignas(16) short wbl[2][8192];   // 2 x 16KB stage buffers
    __shared__ float wwlds[1024];                //  4 KB
    __shared__ unsigned short rc[NWV][CAPW];     //  6 KB (row<<10 | code)
    __shared__ unsigned short dqv[NWV][CAPW];    //  6 KB (f16 of dist - zz)
    __shared__ float zz_l[NWV][32], band_l[NWV][32], thrm[NWV][32];
    __shared__ unsigned rowminU[NWV][32];
    __shared__ unsigned long long bestk[NWV][32];
    __shared__ double wsum[NWV];

    const int tid = threadIdx.x;
    const int wv = tid >> 6, l = tid & 63;
    const int c15 = l & 15, g = l >> 4;
    const int b0 = blockIdx.x << 7;              // 128 rows per block
    const int rbase = b0 + (wv << 5);            // 32 rows per wave
    const int flag = flagp[0];
    const bool fb0 = !(flag == 0 || flag == 1);

    // 256 threads x 4 x 16B = 16 KB stage (linear; contiguous dest)
#define STAGE(T, BUF) do {                                                    \
        const char* _s = (const char*)wb + (size_t)(T) * 16384 + tid * 16;    \
        char* _d = (char*)&wbl[BUF][0] + tid * 16;                            \
        gload_lds16(_s,          _d);                                         \
        gload_lds16(_s +  4096,  _d +  4096);                                 \
        gload_lds16(_s +  8192,  _d +  8192);                                 \
        gload_lds16(_s + 12288,  _d + 12288);                                 \
    } while (0)

    STAGE(0, 0);   // latency hides under the prologue

    if (l < 32) {
        rowminU[wv][l] = 0xFFFFFFFFu;
        bestk[wv][l]   = ~0ull;
    }
    reinterpret_cast<float4*>(wwlds)[tid] = reinterpret_cast<const float4*>(ww)[tid];

    // ---- per-row zz + band: 8-row load batches; per-row tree bit-identical.
    #pragma unroll 1
    for (int qb = 0; qb < 4; ++qb) {
        float4 vrow[8];
        #pragma unroll
        for (int r = 0; r < 8; ++r)
            vrow[r] = *reinterpret_cast<const float4*>(
                z + ((size_t)(rbase + qb * 8 + r) << 8) + (l << 2));
        #pragma unroll
        for (int r = 0; r < 8; ++r) {
            const float4 v = vrow[r];
            float s = v.x * v.x + v.y * v.y + v.z * v.z + v.w * v.w;
            float a = fabsf(v.x) + fabsf(v.y) + fabsf(v.z) + fabsf(v.w);
            #pragma unroll
            for (int off = 32; off; off >>= 1) {
                s += __shfl_xor(s, off, 64);
                a += __shfl_xor(a, off, 64);
            }
            if (l == 0) {
                zz_l[wv][qb * 8 + r]   = s;
                band_l[wv][qb * 8 + r] = a * 2.0e-5f + 1.0e-3f;
            }
        }
    }

    bool fbw = fb0;
    int n = 0;

    int ml[4], cl[4];
    #pragma unroll
    for (int reg = 0; reg < 4; ++reg) {
        if (flag == 1) { ml[reg] = c15;          cl[reg] = 4 * g + reg; }
        else           { ml[reg] = 4 * g + reg;  cl[reg] = c15;         }
    }

    // A fragments: TWO 16-row sets (rows rbase+0..15 and rbase+16..31)
    bf16x8 afr0[8], afr1[8];
    {
        const float* zr0 = z + ((size_t)(rbase + c15) << 8) + (g << 3);
        const float* zr1 = z + ((size_t)(rbase + 16 + c15) << 8) + (g << 3);
        #pragma unroll
        for (int m = 0; m < 8; ++m) {
            float4 lo = *reinterpret_cast<const float4*>(zr0 + (m << 5));
            float4 hi = *reinterpret_cast<const float4*>(zr0 + (m << 5) + 4);
            bf16x8 f;
            f[0] = (short)f2bf(lo.x); f[1] = (short)f2bf(lo.y);
            f[2] = (short)f2bf(lo.z); f[3] = (short)f2bf(lo.w);
            f[4] = (short)f2bf(hi.x); f[5] = (short)f2bf(hi.y);
            f[6] = (short)f2bf(hi.z); f[7] = (short)f2bf(hi.w);
            afr0[m] = f;
        }
        #pragma unroll
        for (int m = 0; m < 8; ++m) {
            float4 lo = *reinterpret_cast<const float4*>(zr1 + (m << 5));
            float4 hi = *reinterpret_cast<const float4*>(zr1 + (m << 5) + 4);
            bf16x8 f;
            f[0] = (short)f2bf(lo.x); f[1] = (short)f2bf(lo.y);
            f[2] = (short)f2bf(lo.z); f[3] = (short)f2bf(lo.w);
            f[4] = (short)f2bf(hi.x); f[5] = (short)f2bf(hi.y);
            f[6] = (short)f2bf(hi.z); f[7] = (short)f2bf(hi.w);
            afr1[m] = f;
        }
    }

    __syncthreads();   // stage 0 landed + all init visible

    float zzv0[4], bdv0[4], zzv1[4], bdv1[4];
    #pragma unroll
    for (int reg = 0; reg < 4; ++reg) {
        zzv0[reg] = zz_l[wv][ml[reg]];
        bdv0[reg] = band_l[wv][ml[reg]];
        zzv1[reg] = zz_l[wv][16 + ml[reg]];
        bdv1[reg] = band_l[wv][16 + ml[reg]];
    }

    float rm0[4] = {INFINITY, INFINITY, INFINITY, INFINITY};
    float rm1[4] = {INFINITY, INFINITY, INFINITY, INFINITY};
    int base = 0;

    // dist + optional collect + optional running-min, per reg. Order within
    // a (t,h): rowset0 regs 0-3 then rowset1 regs 0-3 (base stays coherent).
#define PROCESS(ACC, ZZV, BDV, RM, ROWOFF, DOCOL, DOFM, TCODE)                \
    _Pragma("unroll")                                                         \
    for (int reg = 0; reg < 4; ++reg) {                                       \
        const int _code = ((TCODE) << 5) + (h << 4) + cl[reg];                \
        const float _dist = ((ZZV)[reg] - 2.0f * (ACC)[reg]) + wwlds[_code];  \
        if (DOCOL) {                                                          \
            const bool _pred = (_dist <= (RM)[reg] + (BDV)[reg]);             \
            const unsigned long long _mask = __ballot(_pred);                 \
            if (_mask) {                                                      \
                if (_pred) {                                                  \
                    const int _slot = base + (int)__popcll(_mask & ((1ull << l) - 1ull)); \
                    if (_slot < CAPW) {                                       \
                        rc[wv][_slot] = (unsigned short)((((ROWOFF) + ml[reg]) << 10) | _code); \
                        union { _Float16 h16; unsigned short u; } _cv;        \
                        _cv.h16 = (_Float16)(_dist - (ZZV)[reg]);             \
                        dqv[wv][_slot] = _cv.u;                               \
                    }                                                         \
                }                                                             \
                base += (int)__popcll(_mask);                                 \
            }                                                                 \
        }                                                                     \
        if (DOFM) (RM)[reg] = fminf((RM)[reg], _dist);                        \
    }

#define MINSYNC(RM)                                                           \
    if (flag == 1) {                                                          \
        _Pragma("unroll")                                                     \
        for (int reg = 0; reg < 4; ++reg) {                                   \
            (RM)[reg] = fminf((RM)[reg], __shfl_xor((RM)[reg], 16, 64));      \
            (RM)[reg] = fminf((RM)[reg], __shfl_xor((RM)[reg], 32, 64));      \
        }                                                                     \
    } else {                                                                  \
        _Pragma("unroll")                                                     \
        for (int reg = 0; reg < 4; ++reg) {                                   \
            (RM)[reg] = fminf((RM)[reg], __shfl_xor((RM)[reg], 1, 64));       \
            (RM)[reg] = fminf((RM)[reg], __shfl_xor((RM)[reg], 2, 64));       \
            (RM)[reg] = fminf((RM)[reg], __shfl_xor((RM)[reg], 4, 64));       \
            (RM)[reg] = fminf((RM)[reg], __shfl_xor((RM)[reg], 8, 64));       \
        }                                                                     \
    }

    if (!fb0) {
        #pragma unroll 1
        for (int t = 0; t < 32; ++t) {
            if (t < 31) STAGE(t + 1, (t + 1) & 1);   // prefetch next stage

            const short* sb = wbl[t & 1];
            #pragma unroll
            for (int h = 0; h < 2; ++h) {
                f32x4 a0 = {0.f, 0.f, 0.f, 0.f};
                f32x4 a1 = {0.f, 0.f, 0.f, 0.f};
                #pragma unroll
                for (int m = 0; m < 8; ++m) {
                    bf16x8 bfr = *reinterpret_cast<const bf16x8*>(
                        &sb[((h * 8 + m) << 9) + (l << 3)]);   // linear: conflict-free
                    a0 = __builtin_amdgcn_mfma_f32_16x16x32_bf16(afr0[m], bfr, a0, 0, 0, 0);
                    a1 = __builtin_amdgcn_mfma_f32_16x16x32_bf16(afr1[m], bfr, a1, 0, 0, 0);
                }
                if (t > 0) {
                    PROCESS(a0, zzv0, bdv0, rm0, 0,  1, 1, t)
                    PROCESS(a1, zzv1, bdv1, rm1, 16, 1, 1, t)
                } else {
                    PROCESS(a0, zzv0, bdv0, rm0, 0,  0, 1, t)
                    PROCESS(a1, zzv1, bdv1, rm1, 16, 0, 1, t)
                }
            }

            // ---- cross-lane ROW-min sync (both rowsets)
            MINSYNC(rm0)
            MINSYNC(rm1)
            __syncthreads();   // drains next-stage DMA + releases buffer t&1
        }

        // ---- stage-0 revisit with the final (full-sweep) threshold
        STAGE(0, 0);
        __syncthreads();
        {
            const short* sb = wbl[0];
            #pragma unroll
            for (int h = 0; h < 2; ++h) {
                f32x4 a0 = {0.f, 0.f, 0.f, 0.f};
                f32x4 a1 = {0.f, 0.f, 0.f, 0.f};
                #pragma unroll
                for (int m = 0; m < 8; ++m) {
                    bf16x8 bfr = *reinterpret_cast<const bf16x8*>(
                        &sb[((h * 8 + m) << 9) + (l << 3)]);
                    a0 = __builtin_amdgcn_mfma_f32_16x16x32_bf16(afr0[m], bfr, a0, 0, 0, 0);
                    a1 = __builtin_amdgcn_mfma_f32_16x16x32_bf16(afr1[m], bfr, a1, 0, 0, 0);
                }
                PROCESS(a0, zzv0, bdv0, rm0, 0,  1, 0, 0)
                PROCESS(a1, zzv1, bdv1, rm1, 16, 1, 0, 0)
            }
        }

        n = base;
        if (n > CAPW) fbw = true;

        // per-row approx min -> post-filter threshold (own-wave, in-order)
        #pragma unroll
        for (int reg = 0; reg < 4; ++reg) {
            atomicMin(&rowminU[wv][ml[reg]],      encf(rm0[reg]));
            atomicMin(&rowminU[wv][16 + ml[reg]], encf(rm1[reg]));
        }
        if (l < 32)
            thrm[wv][l] = (decf(rowminU[wv][l]) + band_l[wv][l]) - zz_l[wv][l] + 4.0e-4f;
    }
#undef PROCESS
#undef MINSYNC
#undef STAGE

    // ---- post-filtered exact rescore (bit-identical chain) + consistency net
    if (!fbw) {
        int viol = 0;
        #pragma unroll 1
        for (int i = l; i < n; i += 64) {
            const int e = rc[wv][i];
            const int m = e >> 10, code = e & 1023;
            union { _Float16 h16; unsigned short u; } cv;
            cv.u = dqv[wv][i];
            const float dval = (float)cv.h16;
            if (dval <= thrm[wv][m]) {
                const float dot = chain_dot(z + ((size_t)(rbase + m) << 8),
                                            w + ((size_t)code << 8));
                const float dist = (zz_l[wv][m] - 2.0f * dot) + wwlds[code];
                if (fabsf((dval + zz_l[wv][m]) - dist) > band_l[wv][m] + 4.0e-4f)
                    viol = 1;
                atomicMin(&bestk[wv][m],
                          ((unsigned long long)encf(dist) << 32) | (unsigned)code);
            }
        }
        if (__any(viol)) fbw = true;
    }
    if (fbw) {
        // exhaustive exact fallback (bestk min over superset stays correct)
        #pragma unroll 1
        for (int m = 0; m < 32; ++m) {
            const float zzm = zz_l[wv][m];
            const float* zp = z + ((size_t)(rbase + m) << 8);
            for (int code = l; code < 1024; code += 64) {
                const float dist = (zzm - 2.0f * chain_dot(zp, w + ((size_t)code << 8)))
                                 + wwlds[code];
                atomicMin(&bestk[wv][m],
                          ((unsigned long long)encf(dist) << 32) | (unsigned)code);
            }
        }
    }

    // ---- indices out (ties: lowest code via packed key = numpy argmin)
    if (l < 32) {
        const int code = (int)(unsigned)(bestk[wv][l] & 0xFFFFFFFFull);
        idxf_out[rbase + l] = (float)code;
    }

    // ---- zq gather write: w rows are L2-resident; NO z re-read
    #pragma unroll 4
    for (int rr = 0; rr < 32; ++rr) {
        const int code = (int)(unsigned)(bestk[wv][rr] & 0xFFFFFFFFull);
        const float4 wv4 = *reinterpret_cast<const float4*>(
            w + ((size_t)code << 8) + (l << 2));
        *reinterpret_cast<float4*>(
            zq_out + ((size_t)(rbase + rr) << 8) + (l << 2)) = wv4;
    }

    // ---- loss from winning exact distances: sum_rows dist == sum (zq-z)^2
    double s = 0.0;
    if (l < 32) s = (double)decf((unsigned)(bestk[wv][l] >> 32));
    #pragma unroll
    for (int off = 32; off; off >>= 1) s += __shfl_xor(s, off, 64);
    if (l == 0) wsum[wv] = s;
    __syncthreads();
    if (tid == 0) {
        double t = 0.0;
        #pragma unroll
        for (int i = 0; i < NWV; ++i) t += wsum[i];
        partial[blockIdx.x] = t;
    }
}

// ---------------------------------------------------------------------------
__global__ void finalize_loss_kernel(const double* __restrict__ partial,
                                     float* __restrict__ out) {
    __shared__ double sd[256];
    const int t = threadIdx.x;
    double s = 0.0;
    for (int i = t; i < 512; i += 256) s += partial[i];
    sd[t] = s;
    __syncthreads();
    #pragma unroll
    for (int off = 128; off; off >>= 1) {
        if (t < off) sd[t] += sd[t + off];
        __syncthreads();
    }
    if (t == 0) {
        double mse = sd[0] / ((double)B_N * (double)D_N);
        out[0] = (float)(mse * 1.25);   // vq_loss = mse + 0.25*mse
    }
}

// ---------------------------------------------------------------------------
extern "C" void kernel_launch(void* const* d_in, const int* in_sizes, int n_in,
                              void* d_out, int out_size, void* d_ws, size_t ws_size,
                              hipStream_t stream) {
    const float* z = (const float*)d_in[0];   // [65536, 256]
    const float* w = (const float*)d_in[1];   // [1024, 256]

    float* out  = (float*)d_out;
    float* zq   = out;                        // [65536*256]
    float* loss = out + (size_t)B_N * D_N;    // [1]
    float* idxf = loss + 1;                   // [65536]

    // ws layout (well inside the proven 1,323,008-byte footprint)
    char* wsb = (char*)d_ws;
    float*          ww      = (float*)(wsb);                    //   4 KB @ 0
    unsigned short* wb      = (unsigned short*)(wsb + 4096);    // 512 KB
    int*            flag    = (int*)(wsb + 528384);             //   4 B
    double*         partial = (double*)(wsb + 528448);          //   4 KB (512)

    // 1. MFMA decode probe
    mfma_probe_kernel<<<1, 64, 0, stream>>>(flag);

    // 2. codebook prep: exact ww + re-tiled bf16 codebook
    wprep_kernel<<<K_N / 4, 256, 0, stream>>>(w, ww, wb);

    // 3. single-sweep MFMA filter + exact rescore + fused gather/loss
    //    4 waves/block, 32 rows/wave, 128 rows/block, grid 512, 3 blocks/CU
    vq_mfma_kernel<<<B_N / 128, 256, 0, stream>>>(z, w, wb, ww, flag,
                                                  zq, idxf, partial);

    // 4. finalize loss
    finalize_loss_kernel<<<1, 256, 0, stream>>>(partial, loss);
}

// Round 6
// 167.332 us; speedup vs baseline: 1.2725x; 1.2725x over previous
//
#include <hip/hip_runtime.h>
#include <math.h>

#define B_N 65536
#define K_N 1024
#define D_N 256
#define CAPW 512
#define NWV 8            // waves per block (512 threads, 128 rows/block)

typedef __attribute__((ext_vector_type(8))) short bf16x8;
typedef __attribute__((ext_vector_type(4))) float f32x4;

// RNE float -> bf16 bits
__device__ __forceinline__ unsigned short f2bf(float f) {
    unsigned u = __float_as_uint(f);
    return (unsigned short)((u + 0x7FFFu + ((u >> 16) & 1u)) >> 16);
}
// monotone float <-> u32 order encoding
__device__ __forceinline__ unsigned encf(float f) {
    unsigned u = __float_as_uint(f);
    return u ^ ((unsigned)((int)u >> 31) | 0x80000000u);
}
__device__ __forceinline__ float decf(unsigned e) {
    unsigned u = (e & 0x80000000u) ? (e ^ 0x80000000u) : ~e;
    return __uint_as_float(u);
}
__device__ __forceinline__ void gload_lds16(const void* g, void* l) {
    __builtin_amdgcn_global_load_lds(
        (const __attribute__((address_space(1))) unsigned int*)g,
        (__attribute__((address_space(3))) unsigned int*)l, 16, 0, 0);
}

// THE exact dot chain (bit-identical to the chain validated rounds 1-5/8/11).
__device__ __forceinline__ float chain_dot(const float* __restrict__ zp,
                                           const float* __restrict__ wp) {
    float acc = 0.0f;
    #pragma unroll 1
    for (int j = 0; j < 64; ++j) {
        float4 za = *reinterpret_cast<const float4*>(zp + (j << 2));
        float4 wa = *reinterpret_cast<const float4*>(wp + (j << 2));
        acc = fmaf(za.x, wa.x, acc);
        acc = fmaf(za.y, wa.y, acc);
        acc = fmaf(za.z, wa.z, acc);
        acc = fmaf(za.w, wa.w, acc);
    }
    return acc;
}

// ---------------------------------------------------------------------------
// MFMA decode probe (validated rounds 8-11). flag: 0=H1, 1=swapped, 2=bad.
// ---------------------------------------------------------------------------
__device__ __forceinline__ int pA(int i, int k) {
    return ((i + k) & 15) - 7 + 9 * ((k >> 4) & 1);
}
__device__ __forceinline__ int pB(int j, int k) {
    return ((j + 3 * k) & 15) - 7 + 5 * ((k >> 4) & 1);
}

__global__ void mfma_probe_kernel(int* __restrict__ flag) {
    const int l = threadIdx.x & 63;
    const int c15 = l & 15, g = l >> 4;
    bf16x8 afr[8], bfr[8];
    #pragma unroll
    for (int m = 0; m < 8; ++m)
        #pragma unroll
        for (int e = 0; e < 8; ++e) {
            const int k = m * 32 + g * 8 + e;
            afr[m][e] = (short)f2bf((float)pA(c15, k));
            bfr[m][e] = (short)f2bf((float)pB(c15, k));
        }
    f32x4 acc = {0.f, 0.f, 0.f, 0.f};
    #pragma unroll
    for (int m = 0; m < 8; ++m)
        acc = __builtin_amdgcn_mfma_f32_16x16x32_bf16(afr[m], bfr[m], acc, 0, 0, 0);
    int h1 = 1, h2 = 1;
    #pragma unroll 1
    for (int reg = 0; reg < 4; ++reg) {
        const int q = 4 * g + reg;
        int e1 = 0, e2 = 0;
        for (int k = 0; k < 32; ++k) {        // patterns are 32-periodic in k
            e1 += pA(q, k) * pB(c15, k);
            e2 += pA(c15, k) * pB(q, k);
        }
        e1 *= 8; e2 *= 8;
        if (acc[reg] != (float)e1) h1 = 0;
        if (acc[reg] != (float)e2) h2 = 0;
    }
    h1 = __all(h1); h2 = __all(h2);
    if (threadIdx.x == 0) *flag = h1 ? 0 : (h2 ? 1 : 2);
}

// ---------------------------------------------------------------------------
// ww (validated tree) + bf16 codebook re-tiled for linear LDS fragment reads
// (validated r10/r11 layout).
// ---------------------------------------------------------------------------
__global__ void wprep_kernel(const float* __restrict__ w,
                             float* __restrict__ ww,
                             unsigned short* __restrict__ wb) {
    int wave = (int)((blockIdx.x * blockDim.x + threadIdx.x) >> 6);
    int lane = threadIdx.x & 63;
    if (wave >= K_N) return;
    const float4 v = *reinterpret_cast<const float4*>(w + ((size_t)wave << 8) + (lane << 2));
    float s = v.x * v.x + v.y * v.y + v.z * v.z + v.w * v.w;
    #pragma unroll
    for (int off = 32; off; off >>= 1) s += __shfl_xor(s, off, 64);
    if (lane == 0) ww[wave] = s;
    ushort4 b;
    b.x = f2bf(v.x); b.y = f2bf(v.y); b.z = f2bf(v.z); b.w = f2bf(v.w);
    const int mp = lane >> 3;
    const int gp = (lane >> 1) & 3;
    const int hp = (wave >> 4) & 1;
    const size_t off_b = (size_t)(wave >> 5) * 16384
        + (size_t)(((hp * 8 + mp) * 64 + gp * 16 + (wave & 15)) * 16)
        + (size_t)((lane & 1) * 8);
    *reinterpret_cast<ushort4*>((char*)wb + off_b) = b;
}

// ---------------------------------------------------------------------------
// Main kernel.
// r17: REVERT to the r15/r4 geometry (8 waves/512 thr/128 rows, grid 512,
//   16 waves/CU all-resident — r16's 2x-rows variant halved residency and
//   regressed 173->213). Single change vs r4: FUSED prologue. The zz/band
//   pass is merged into the A-fragment loads (z read ONCE): each lane sums
//   squares/abs over its 64 row-elements, then shfl_xor(16/32) reduces the
//   4 lanes sharing a row. Deletes a full 64 MB z pass + 32 shuffle-trees
//   of serial prologue per wave. zz/band summation order changes (flagged):
//   zz used consistently in filter+rescore; band keeps >=2x slack vs the
//   bf16 bound; viol-net + exact fallback still guarantee the argmin.
// r15 (kept): loss-from-dist epilogue (no z re-read; w gather L2-resident).
// r14/r13 (kept): T15 compute/process pipeline + 3-buffer counted-vmcnt
//   staging, bit-identical collection order.
// ---------------------------------------------------------------------------
__global__ __launch_bounds__(512, 4)
void vq_mfma_kernel(const float* __restrict__ z, const float* __restrict__ w,
                    const unsigned short* __restrict__ wb,
                    const float* __restrict__ ww,
                    const int* __restrict__ flagp,
                    float* __restrict__ zq_out,
                    float* __restrict__ idxf_out,
                    double* __restrict__ partial) {
    __shared__ alignas(16) short wbl[3][8192];   // 3 x 16KB stage buffers
    __shared__ float wwlds[1024];                //  4 KB
    __shared__ unsigned short rc[NWV][CAPW];     //  8 KB (row<<10 | code)
    __shared__ unsigned short dqv[NWV][CAPW];    //  8 KB (f16 of dist - zz)
    __shared__ float zz_l[NWV][16], band_l[NWV][16], thrm[NWV][16];
    __shared__ unsigned rowminU[NWV][16];
    __shared__ unsigned long long bestk[NWV][16];
    __shared__ double wsum[NWV];

    const int tid = threadIdx.x;
    const int wv = tid >> 6, l = tid & 63;
    const int c15 = l & 15, g = l >> 4;
    const int b0 = blockIdx.x << 7;              // 128 rows per block
    const int rbase = b0 + (wv << 4);
    const int flag = flagp[0];
    const bool fb0 = !(flag == 0 || flag == 1);

    // 512 threads x 2 x 16B = 16 KB stage (linear; per-wave contiguous dest)
#define STAGE(T, BUF) do {                                                    \
        const char* _s = (const char*)wb + (size_t)(T) * 16384 + tid * 16;    \
        char* _d = (char*)&wbl[BUF][0] + tid * 16;                            \
        gload_lds16(_s,         _d);                                          \
        gload_lds16(_s + 8192,  _d + 8192);                                   \
    } while (0)

    STAGE(0, 0);   // latency hides under the prologue

    if (l < 16) {
        rowminU[wv][l] = 0xFFFFFFFFu;
        bestk[wv][l]   = ~0ull;
    }
    reinterpret_cast<float2*>(wwlds)[tid] = reinterpret_cast<const float2*>(ww)[tid];

    bool fbw = fb0;
    int n = 0;

    int ml[4], cl[4];
    #pragma unroll
    for (int reg = 0; reg < 4; ++reg) {
        if (flag == 1) { ml[reg] = c15;          cl[reg] = 4 * g + reg; }
        else           { ml[reg] = 4 * g + reg;  cl[reg] = c15;         }
    }

    // ---- FUSED single z pass: A fragments + exact zz/band from the same
    //      registers. Lane l holds row rbase+c15, cols g*8 + m*32 .. +7.
    //      The 4 lanes sharing a row (l ^ 16, l ^ 32) reduce to full-row
    //      zz (sum sq) and abs-sum via 2 shfl_xor steps.
    bf16x8 afr[8];
    {
        const float* zr = z + ((size_t)(rbase + c15) << 8) + (g << 3);
        float s = 0.0f, a = 0.0f;
        #pragma unroll
        for (int m = 0; m < 8; ++m) {
            float4 lo = *reinterpret_cast<const float4*>(zr + (m << 5));
            float4 hi = *reinterpret_cast<const float4*>(zr + (m << 5) + 4);
            s += lo.x * lo.x + lo.y * lo.y + lo.z * lo.z + lo.w * lo.w;
            s += hi.x * hi.x + hi.y * hi.y + hi.z * hi.z + hi.w * hi.w;
            a += fabsf(lo.x) + fabsf(lo.y) + fabsf(lo.z) + fabsf(lo.w);
            a += fabsf(hi.x) + fabsf(hi.y) + fabsf(hi.z) + fabsf(hi.w);
            bf16x8 f;
            f[0] = (short)f2bf(lo.x); f[1] = (short)f2bf(lo.y);
            f[2] = (short)f2bf(lo.z); f[3] = (short)f2bf(lo.w);
            f[4] = (short)f2bf(hi.x); f[5] = (short)f2bf(hi.y);
            f[6] = (short)f2bf(hi.z); f[7] = (short)f2bf(hi.w);
            afr[m] = f;
        }
        s += __shfl_xor(s, 16, 64);
        s += __shfl_xor(s, 32, 64);
        a += __shfl_xor(a, 16, 64);
        a += __shfl_xor(a, 32, 64);
        if (g == 0) {                      // lanes 0..15 write rows 0..15
            zz_l[wv][c15]   = s;
            band_l[wv][c15] = a * 2.0e-5f + 1.0e-3f;   // >=2x rigorous bf16 bound
        }
    }

    STAGE(1, 1);   // second prefetch in flight before the first sync

    __syncthreads();   // stages 0+1 landed + all init visible (full drain, once)

    float zzv[4], bdv[4];
    #pragma unroll
    for (int reg = 0; reg < 4; ++reg) {
        zzv[reg] = zz_l[wv][ml[reg]];     // own-wave LDS, in-order
        bdv[reg] = band_l[wv][ml[reg]];
    }

    float runmin[4] = {INFINITY, INFINITY, INFINITY, INFINITY};
    int base = 0;

    // One pipelined iteration. C: iteration index (0..33).
    //   compute (C<=32): tile (C<=31 ? C : 0) from wbl[C%3] into CUR0/CUR1
    //   process (C>=1):  tile (C<=32 ? C-1 : 0) from PRV0/PRV1
    //   STAGE   (C<=30): src tile (C+2<=31 ? C+2 : 0) -> wbl[(C+2)%3]
    //   barrier (C<=31): vmcnt(2) while C<=30 else vmcnt(0)
#define ITER(C, CUR0, CUR1, PRV0, PRV1) do {                                  \
    if ((C) <= 32) {                                                          \
        if ((C) <= 30) {                                                      \
            const int _st = ((C) + 2 <= 31) ? ((C) + 2) : 0;                  \
            STAGE(_st, ((C) + 2) % 3);                                        \
        }                                                                     \
        const short* _sb = wbl[(C) % 3];                                      \
        CUR0 = (f32x4){0.f, 0.f, 0.f, 0.f};                                   \
        CUR1 = (f32x4){0.f, 0.f, 0.f, 0.f};                                   \
        _Pragma("unroll")                                                     \
        for (int m = 0; m < 8; ++m) {                                         \
            bf16x8 _b = *reinterpret_cast<const bf16x8*>(                     \
                &_sb[(m << 9) + (l << 3)]);                                   \
            CUR0 = __builtin_amdgcn_mfma_f32_16x16x32_bf16(afr[m], _b, CUR0, 0, 0, 0); \
        }                                                                     \
        _Pragma("unroll")                                                     \
        for (int m = 0; m < 8; ++m) {                                         \
            bf16x8 _b = *reinterpret_cast<const bf16x8*>(                     \
                &_sb[((8 + m) << 9) + (l << 3)]);                             \
            CUR1 = __builtin_amdgcn_mfma_f32_16x16x32_bf16(afr[m], _b, CUR1, 0, 0, 0); \
        }                                                                     \
    }                                                                         \
    if ((C) >= 1) {                                                           \
        const int _tc = ((C) <= 32) ? ((C) - 1) : 0;                          \
        const bool _docol = ((C) >= 2);                                       \
        const bool _dofm = ((C) <= 32);                                       \
        _Pragma("unroll")                                                     \
        for (int h = 0; h < 2; ++h) {                                         \
            const f32x4 _acc = h ? (PRV1) : (PRV0);                           \
            _Pragma("unroll")                                                 \
            for (int reg = 0; reg < 4; ++reg) {                               \
                const int _code = (_tc << 5) + (h << 4) + cl[reg];            \
                const float _dist = (zzv[reg] - 2.0f * _acc[reg]) + wwlds[_code]; \
                if (_docol) {                                                 \
                    const bool _pred = (_dist <= runmin[reg] + bdv[reg]);     \
                    const unsigned long long _mask = __ballot(_pred);         \
                    if (_mask) {                                              \
                        if (_pred) {                                          \
                            const int _slot = base + (int)__popcll(_mask & ((1ull << l) - 1ull)); \
                            if (_slot < CAPW) {                               \
                                rc[wv][_slot] = (unsigned short)((ml[reg] << 10) | _code); \
                                union { _Float16 h16; unsigned short u; } _cv; \
                                _cv.h16 = (_Float16)(_dist - zzv[reg]);       \
                                dqv[wv][_slot] = _cv.u;                       \
                            }                                                 \
                        }                                                     \
                        base += (int)__popcll(_mask);                         \
                    }                                                         \
                }                                                             \
                if (_dofm) runmin[reg] = fminf(runmin[reg], _dist);           \
            }                                                                 \
        }                                                                     \
        if (_dofm) {                                                          \
            if (flag == 1) {                                                  \
                _Pragma("unroll")                                             \
                for (int reg = 0; reg < 4; ++reg) {                           \
                    runmin[reg] = fminf(runmin[reg], __shfl_xor(runmin[reg], 16, 64)); \
                    runmin[reg] = fminf(runmin[reg], __shfl_xor(runmin[reg], 32, 64)); \
                }                                                             \
            } else {                                                          \
                _Pragma("unroll")                                             \
                for (int reg = 0; reg < 4; ++reg) {                           \
                    runmin[reg] = fminf(runmin[reg], __shfl_xor(runmin[reg], 1, 64)); \
                    runmin[reg] = fminf(runmin[reg], __shfl_xor(runmin[reg], 2, 64)); \
                    runmin[reg] = fminf(runmin[reg], __shfl_xor(runmin[reg], 4, 64)); \
                    runmin[reg] = fminf(runmin[reg], __shfl_xor(runmin[reg], 8, 64)); \
                }                                                             \
            }                                                                 \
        }                                                                     \
    }                                                                         \
    if ((C) <= 31) {                                                          \
        if ((C) <= 30) { asm volatile("s_waitcnt vmcnt(2) lgkmcnt(0)" ::: "memory"); } \
        else           { asm volatile("s_waitcnt vmcnt(0) lgkmcnt(0)" ::: "memory"); } \
        __builtin_amdgcn_sched_barrier(0);                                    \
        __builtin_amdgcn_s_barrier();                                         \
        __builtin_amdgcn_sched_barrier(0);                                    \
    }                                                                         \
} while (0)

    if (!fb0) {
        f32x4 aA0 = {0.f, 0.f, 0.f, 0.f}, aA1 = {0.f, 0.f, 0.f, 0.f};
        f32x4 aB0 = {0.f, 0.f, 0.f, 0.f}, aB1 = {0.f, 0.f, 0.f, 0.f};
        // 34 iterations as 17 even/odd pairs; acc sets are NAMED (no runtime
        // indexing -> stays in registers, rule #20).
        #pragma unroll 1
        for (int c = 0; c < 34; c += 2) {
            ITER(c,     aA0, aA1, aB0, aB1);   // even: compute A, process B
            ITER(c + 1, aB0, aB1, aA0, aA1);   // odd:  compute B, process A
        }

        n = base;
        if (n > CAPW) fbw = true;

        // per-row approx min -> post-filter threshold (own-wave, in-order)
        #pragma unroll
        for (int reg = 0; reg < 4; ++reg)
            atomicMin(&rowminU[wv][ml[reg]], encf(runmin[reg]));
        if (l < 16)
            thrm[wv][l] = (decf(rowminU[wv][l]) + band_l[wv][l]) - zz_l[wv][l] + 4.0e-4f;
    }
#undef ITER
#undef STAGE

    // ---- post-filtered exact rescore (bit-identical chain) + consistency net
    if (!fbw) {
        int viol = 0;
        #pragma unroll 1
        for (int i = l; i < n; i += 64) {
            const int e = rc[wv][i];
            const int m = e >> 10, code = e & 1023;
            union { _Float16 h16; unsigned short u; } cv;
            cv.u = dqv[wv][i];
            const float dval = (float)cv.h16;
            if (dval <= thrm[wv][m]) {
                const float dot = chain_dot(z + ((size_t)(rbase + m) << 8),
                                            w + ((size_t)code << 8));
                const float dist = (zz_l[wv][m] - 2.0f * dot) + wwlds[code];
                if (fabsf((dval + zz_l[wv][m]) - dist) > band_l[wv][m] + 4.0e-4f)
                    viol = 1;
                atomicMin(&bestk[wv][m],
                          ((unsigned long long)encf(dist) << 32) | (unsigned)code);
            }
        }
        if (__any(viol)) fbw = true;
    }
    if (fbw) {
        // exhaustive exact fallback (bestk min over superset stays correct)
        #pragma unroll 1
        for (int m = 0; m < 16; ++m) {
            const float zzm = zz_l[wv][m];
            const float* zp = z + ((size_t)(rbase + m) << 8);
            for (int code = l; code < 1024; code += 64) {
                const float dist = (zzm - 2.0f * chain_dot(zp, w + ((size_t)code << 8)))
                                 + wwlds[code];
                atomicMin(&bestk[wv][m],
                          ((unsigned long long)encf(dist) << 32) | (unsigned)code);
            }
        }
    }

    // ---- indices out (ties: lowest code via packed key = numpy argmin)
    if (l < 16) {
        const int code = (int)(unsigned)(bestk[wv][l] & 0xFFFFFFFFull);
        idxf_out[rbase + l] = (float)code;
    }

    // ---- zq gather write: w rows are L2-resident; NO z re-read
    int codes[16];
    #pragma unroll
    for (int rr = 0; rr < 16; ++rr)
        codes[rr] = (int)(unsigned)(bestk[wv][rr] & 0xFFFFFFFFull);
    #pragma unroll 4
    for (int rr = 0; rr < 16; ++rr) {
        const float4 wv4 = *reinterpret_cast<const float4*>(
            w + ((size_t)codes[rr] << 8) + (l << 2));
        *reinterpret_cast<float4*>(
            zq_out + ((size_t)(rbase + rr) << 8) + (l << 2)) = wv4;
    }

    // ---- loss from winning exact distances: sum_rows dist == sum (zq-z)^2
    double s = 0.0;
    if (l < 16) s = (double)decf((unsigned)(bestk[wv][l] >> 32));
    #pragma unroll
    for (int off = 8; off; off >>= 1) s += __shfl_xor(s, off, 64);
    if (l == 0) wsum[wv] = s;
    __syncthreads();
    if (tid == 0) {
        double t = 0.0;
        #pragma unroll
        for (int i = 0; i < NWV; ++i) t += wsum[i];
        partial[blockIdx.x] = t;
    }
}

// ---------------------------------------------------------------------------
__global__ void finalize_loss_kernel(const double* __restrict__ partial,
                                     float* __restrict__ out) {
    __shared__ double sd[256];
    const int t = threadIdx.x;
    double s = 0.0;
    for (int i = t; i < 512; i += 256) s += partial[i];
    sd[t] = s;
    __syncthreads();
    #pragma unroll
    for (int off = 128; off; off >>= 1) {
        if (t < off) sd[t] += sd[t + off];
        __syncthreads();
    }
    if (t == 0) {
        double mse = sd[0] / ((double)B_N * (double)D_N);
        out[0] = (float)(mse * 1.25);   // vq_loss = mse + 0.25*mse
    }
}

// ---------------------------------------------------------------------------
extern "C" void kernel_launch(void* const* d_in, const int* in_sizes, int n_in,
                              void* d_out, int out_size, void* d_ws, size_t ws_size,
                              hipStream_t stream) {
    const float* z = (const float*)d_in[0];   // [65536, 256]
    const float* w = (const float*)d_in[1];   // [1024, 256]

    float* out  = (float*)d_out;
    float* zq   = out;                        // [65536*256]
    float* loss = out + (size_t)B_N * D_N;    // [1]
    float* idxf = loss + 1;                   // [65536]

    // ws layout (well inside the proven 1,323,008-byte footprint)
    char* wsb = (char*)d_ws;
    float*          ww      = (float*)(wsb);                    //   4 KB @ 0
    unsigned short* wb      = (unsigned short*)(wsb + 4096);    // 512 KB
    int*            flag    = (int*)(wsb + 528384);             //   4 B
    double*         partial = (double*)(wsb + 528448);          //   4 KB (512)

    // 1. MFMA decode probe
    mfma_probe_kernel<<<1, 64, 0, stream>>>(flag);

    // 2. codebook prep: exact ww + re-tiled bf16 codebook
    wprep_kernel<<<K_N / 4, 256, 0, stream>>>(w, ww, wb);

    // 3. single-sweep MFMA filter + exact rescore + fused gather/loss
    //    8 waves/block, 128 rows/block, grid = 512 = exactly 2 blocks/CU
    vq_mfma_kernel<<<B_N / 128, 512, 0, stream>>>(z, w, wb, ww, flag,
                                                  zq, idxf, partial);

    // 4. finalize loss
    finalize_loss_kernel<<<1, 256, 0, stream>>>(partial, loss);
}